// Round 6
// baseline (390.905 us; speedup 1.0000x reference)
//
#include <hip/hip_runtime.h>
#include <math.h>

#define NANG 120
#define NB   16
#define H    50
#define SD   100
#define NBIN 51        // rfft bins of length-100
#define PADB 7         // top pad rows of B-hat (rows -7..-1 zero)
#define BROWS 72       // stored rows: r in [-7, 64]
#define BST  106       // B-hat row stride
#define WST  104       // g_W row stride
#define RTST 52        // Rt row stride
#define CLAG 104       // C lag dim (13 tiles * 8)
#define AX   58        // g_Arec x rows (50 real + 8 zero pad)

// ---- device-global scratch ----
__device__ __align__(16) float g_Arec[NB*2*AX*NBIN*2 + 64]; // [b][c][x][om][2], x 50..57 zero
__device__ __align__(16) float g_ligc[NB*2*H*H];            // [b][c][y][x]
__device__ __align__(16) float g_W[H*WST];                  // [y][2*om+p] = (cos, -sin)
__device__ __align__(16) float g_P[NBIN*128 + 64];          // [om][2*dy+p] = (cos,sin), dy 0..49
__device__ float g_resV[NANG*NB];
__device__ int   g_resP[NANG*NB];

// 8-lag tile d0 bases per wave (2 slots, 127 = none). steps/wave/phase <= 56.
__device__ const int g_s8[8][2] = {
  {-1,127},{-9,-49},{7,47},{-17,-41},{15,39},{-25,-33},{23,31},{127,127}
};

// ================= prep: conv+relu+combine, rec spectrum, tables =================
__global__ __launch_bounds__(512) void k_prep(const float* __restrict__ rec,
                                              const float* __restrict__ lig,
                                              const float* __restrict__ wr,
                                              const float* __restrict__ br,
                                              const float* __restrict__ wsc) {
  const int blk = blockIdx.x;
  const int tid = threadIdx.x;
  if (blk == NB) {
    for (int u = tid; u < H*WST; u += 512) {
      int y = u / WST, col = u % WST;
      float v = 0.f;
      if (col < 2*NBIN) {
        int om = col >> 1;
        int k = (om * y) % SD;
        double ang = 6.283185307179586 * (double)k / 100.0;
        v = (col & 1) ? (float)(-sin(ang)) : (float)cos(ang);
      }
      g_W[u] = v;
    }
    for (int u = tid; u < NBIN*128; u += 512) {
      int om = u >> 7, q = u & 127;
      int dy = q >> 1;
      float v = 0.f;
      if (dy <= 49) {
        int k = (om * dy) % SD;
        double ang = 6.283185307179586 * (double)k / 100.0;
        v = (q & 1) ? (float)sin(ang) : (float)cos(ang);
      }
      g_P[u] = v;
    }
    return;
  }
  const int b = blk;
  __shared__ float recf[2*H*H];
  __shared__ float tbl[SD*2];
  for (int k = tid; k < SD; k += 512) {
    double ang = 6.283185307179586 * (double)k / 100.0;
    tbl[2*k]   = (float)cos(ang);
    tbl[2*k+1] = (float)sin(ang);
  }
  const float* rimg = rec + b*H*H;
  const float* limg = lig + b*H*H;
  for (int p = tid; p < H*H; p += 512) {
    int i = p / H, j = p - (p/H)*H;
    float ar0 = br[0], ar1 = br[1], al0 = br[0], al1 = br[1];
    for (int di = 0; di < 3; ++di) {
      int ii = i + di - 1;
      if (ii < 0 || ii >= H) continue;
      for (int dj = 0; dj < 3; ++dj) {
        int jj = j + dj - 1;
        if (jj < 0 || jj >= H) continue;
        float rv = rimg[ii*H+jj], lv = limg[ii*H+jj];
        float w0 = wr[di*3 + dj], w1 = wr[9 + di*3 + dj];
        ar0 += w0*rv; ar1 += w1*rv; al0 += w0*lv; al1 += w1*lv;
      }
    }
    ar0 = fmaxf(ar0, 0.f); ar1 = fmaxf(ar1, 0.f);
    al0 = fmaxf(al0, 0.f); al1 = fmaxf(al1, 0.f);
    recf[p] = ar0; recf[H*H + p] = ar1;
    g_ligc[((b*2+0)*H + i)*H + j] = wsc[0]*al0 + wsc[1]*al1;
    g_ligc[((b*2+1)*H + i)*H + j] = wsc[2]*al0 + wsc[3]*al1;
  }
  for (int u = tid; u < 2*8*102; u += 512) {
    int c = u / 816; int r = u % 816;
    int x = 50 + r / 102; int q = r % 102;
    g_Arec[((b*2+c)*AX + x)*102 + q] = 0.f;
  }
  __syncthreads();
  for (int u = tid; u < 2*H*NBIN; u += 512) {
    int om = u % NBIN; int rest = u / NBIN; int x = rest % H; int c = rest / H;
    const float* row = recf + (c*H + x)*H;
    float sr = 0.f, si = 0.f;
    int k = 0;
    for (int y = 0; y < H; ++y) {
      float rv = row[y];
      sr += rv * tbl[2*k];
      si -= rv * tbl[2*k+1];
      k += om; if (k >= SD) k -= SD;
    }
    float* dst = g_Arec + ((b*2+c)*AX + x)*102 + 2*om;
    dst[0] = sr; dst[1] = si;
  }
}

#define STEP8(uu) do { \
  float Ar = ar_[(uu)&7], Ai = ai_[(uu)&7]; \
  _Pragma("unroll") \
  for (int k = 0; k < 8; ++k) { \
    const int sl = ((uu)+k)&7; \
    acc[2*k]   += Ar*br_[sl] + Ai*bi_[sl]; \
    acc[2*k+1] += Ar*bi_[sl] - Ai*br_[sl]; \
  } \
} while(0)

// 8-lag correlation tile: acc[2k],acc[2k+1] = (cr,ci) for lag d0+k
__device__ __forceinline__ void p3_tile8(int d0, int b, int c, const float* sB, int om,
                                         float (&acc)[16]) {
  const int x_lo = max(0, -(d0+7));
  const int x_hi = min(H, H - d0);
  const int ng = (x_hi - x_lo + 7) >> 3;
  const float* Ap = g_Arec + ((b*2+c)*AX + x_lo)*102 + 2*om;
  const float* Bp = sB + (PADB + x_lo + d0)*BST + 2*om;
  float br_[8], bi_[8], ar_[8], ai_[8];
  #pragma unroll
  for (int s = 0; s < 8; ++s) {
    float2 bv = *(const float2*)&Bp[s*BST];
    br_[s] = bv.x; bi_[s] = bv.y;
    float2 av = *(const float2*)&Ap[s*102];
    ar_[s] = av.x; ai_[s] = av.y;
  }
  #pragma unroll 1
  for (int g = 0; g < ng-1; ++g) {
    #pragma unroll
    for (int u = 0; u < 8; ++u) {
      STEP8(u);
      float2 bv = *(const float2*)&Bp[(u+8)*BST];
      br_[u] = bv.x; bi_[u] = bv.y;
      float2 av = *(const float2*)&Ap[(u+8)*102];
      ar_[u] = av.x; ai_[u] = av.y;
    }
    Bp += 8*BST; Ap += 8*102;
  }
  // final group: B-prefetch only (rows <= 64, all in-bounds; A beyond x_hi is zero)
  #pragma unroll
  for (int u = 0; u < 8; ++u) {
    STEP8(u);
    if (u < 7) {
      float2 bv = *(const float2*)&Bp[(u+8)*BST];
      br_[u] = bv.x; bi_[u] = bv.y;
    }
  }
}

// ================= main: per (angle,batch) block, 512 threads =================
__global__ __launch_bounds__(512, 4) void k_main() {
  const int bid = blockIdx.x;
  const int a = bid % NANG;
  const int b = bid / NANG;
  const int tid = threadIdx.x;

  // LDS (words):
  //   [0..7632)        sB [72][106] (one channel at a time)
  //   [7632..18240)    C region: Cr[51][104], Ci[51][104]
  //                    (Rt0 @ +0, Rt1 @ +2600 live until P2 reads done; C written after)
  //   [18240..18256)   reduction
  __shared__ __align__(16) float sMem[18256];
  float* sB  = sMem;
  float* Rt0 = sMem + 7632;
  float* Rt1 = sMem + 7632 + 2600;
  float* Cr  = sMem + 7632;
  float* Ci  = sMem + 7632 + NBIN*CLAG;
  float* sRedV = sMem + 18240;
  int*   sRedP = (int*)(sMem + 18248);

  // P0: zero pad rows of sB (rows -7..-1 and 50..64 -> stored 0..6, 57..71)
  for (int u = tid; u < 22*BST; u += 512) {
    int r = u / BST;
    int row = (r < PADB) ? r : r + 50;
    sB[row*BST + (u % BST)] = 0.f;
  }

  // P1: bilinear rotation of combined ligand features -> Rt0/Rt1 ([col j][row i])
  float angf = 0.05235987755982988f * (float)a;
  float ca = cosf(angf), sa = sinf(angf);
  const float* L0 = g_ligc + (b*2+0)*H*H;
  const float* L1 = g_ligc + (b*2+1)*H*H;
  for (int p = tid; p < H*H; p += 512) {
    int i = p / H, j = p - (p/H)*H;
    float gy = -1.f + (float)i*(2.f/49.f);
    float gx = -1.f + (float)j*(2.f/49.f);
    float x_in = ca*gx - sa*gy;
    float y_in = sa*gx + ca*gy;
    float px = (x_in + 1.f)*0.5f*49.f;
    float py = (y_in + 1.f)*0.5f*49.f;
    float fx = floorf(px), fy = floorf(py);
    int x0 = (int)fx, y0 = (int)fy;
    int x1 = x0 + 1, y1 = y0 + 1;
    float wx1 = px - fx, wx0 = 1.f - wx1;
    float wy1 = py - fy, wy0 = 1.f - wy1;
    float v0 = 0.f, v1 = 0.f;
    if (y0 >= 0 && y0 < H) {
      if (x0 >= 0 && x0 < H) { float w = wy0*wx0; int o = y0*H+x0; v0 += w*L0[o]; v1 += w*L1[o]; }
      if (x1 >= 0 && x1 < H) { float w = wy0*wx1; int o = y0*H+x1; v0 += w*L0[o]; v1 += w*L1[o]; }
    }
    if (y1 >= 0 && y1 < H) {
      if (x0 >= 0 && x0 < H) { float w = wy1*wx0; int o = y1*H+x0; v0 += w*L0[o]; v1 += w*L1[o]; }
      if (x1 >= 0 && x1 < H) { float w = wy1*wx1; int o = y1*H+x1; v0 += w*L0[o]; v1 += w*L1[o]; }
    }
    Rt0[j*RTST + i] = v0;
    Rt1[j*RTST + i] = v1;
  }
  __syncthreads();

  const int wid = tid >> 6, lane = tid & 63;
  const int om = (lane <= 50) ? lane : 50;
  const bool omValid = (lane <= 50);
  const int d0A = g_s8[wid][0];
  const int d0B = g_s8[wid][1];

  float accA[16], accB[16];
  #pragma unroll
  for (int k = 0; k < 16; ++k) { accA[k] = 0.f; accB[k] = 0.f; }

  #pragma unroll 1
  for (int c = 0; c < 2; ++c) {
    // P2(c): y-DFT of rotated rows -> sB. 425 units (25 row-pairs x 17 col-groups)
    if (tid < 425) {
      int cg = tid % 17;          // col group (6 words), fast across lanes
      int rt = tid / 17;          // 0..24
      int i0 = 2*rt;
      int col0 = 6*cg;
      float pacc[2][6];
      #pragma unroll
      for (int p = 0; p < 2; ++p)
        #pragma unroll
        for (int q = 0; q < 6; ++q) pacc[p][q] = 0.f;
      const float* rtc = (c ? Rt1 : Rt0) + i0;
      const float* wt = g_W + col0;
      #pragma unroll 2
      for (int y = 0; y < H; ++y) {
        float2 rv = *(const float2*)&rtc[y*RTST];
        float ww[6];
        #pragma unroll
        for (int q = 0; q < 3; ++q) {
          float2 w2 = *(const float2*)&wt[y*WST + 2*q];
          ww[2*q] = w2.x; ww[2*q+1] = w2.y;
        }
        float rr[2] = {rv.x, rv.y};
        #pragma unroll
        for (int p = 0; p < 2; ++p)
          #pragma unroll
          for (int q = 0; q < 6; ++q) pacc[p][q] += rr[p]*ww[q];
      }
      float* dst = sB + col0;
      #pragma unroll
      for (int p = 0; p < 2; ++p) {
        int i = i0 + p;
        #pragma unroll
        for (int q = 0; q < 3; ++q) {
          float2 o = {pacc[p][2*q], pacc[p][2*q+1]};
          *(float2*)&dst[(PADB+i)*BST + 2*q] = o;
        }
      }
    }
    __syncthreads();

    // P3(c): 8-lag correlation tiles, accumulate in registers across channels
    if (d0A != 127) p3_tile8(d0A, b, c, sB, om, accA);
    if (d0B != 127) p3_tile8(d0B, b, c, sB, om, accB);
    __syncthreads();   // all sB reads done before next P2 overwrite / C write
  }

  // write accumulators -> Cr/Ci (clobbers dead Rt region)
  if (omValid) {
    const float sc = (om == 0 || om == 50) ? 0.5f : 1.0f;
    if (d0A != 127) {
      int base = om*CLAG + (d0A + 49);
      float4 v0 = {accA[0]*sc, accA[2]*sc, accA[4]*sc, accA[6]*sc};
      float4 v1 = {accA[8]*sc, accA[10]*sc, accA[12]*sc, accA[14]*sc};
      float4 w0 = {accA[1]*sc, accA[3]*sc, accA[5]*sc, accA[7]*sc};
      float4 w1 = {accA[9]*sc, accA[11]*sc, accA[13]*sc, accA[15]*sc};
      *(float4*)&Cr[base] = v0; *(float4*)&Cr[base+4] = v1;
      *(float4*)&Ci[base] = w0; *(float4*)&Ci[base+4] = w1;
    }
    if (d0B != 127) {
      int base = om*CLAG + (d0B + 49);
      float4 v0 = {accB[0]*sc, accB[2]*sc, accB[4]*sc, accB[6]*sc};
      float4 v1 = {accB[8]*sc, accB[10]*sc, accB[12]*sc, accB[14]*sc};
      float4 w0 = {accB[1]*sc, accB[3]*sc, accB[5]*sc, accB[7]*sc};
      float4 w1 = {accB[9]*sc, accB[11]*sc, accB[13]*sc, accB[15]*sc};
      *(float4*)&Cr[base] = v0; *(float4*)&Cr[base+4] = v1;
      *(float4*)&Ci[base] = w0; *(float4*)&Ci[base+4] = w1;
    }
  }
  __syncthreads();

  // P4: inverse DFT along omega with +-dy symmetry, single round (442 units)
  float bestV = 3.0e38f; int bestP = 0;
  if (tid < 442) {
    int lt = tid % 26;          // lag tile: lagIdx 4*lt..4*lt+3
    int dt = tid / 26;          // dy tile: 3*dt..3*dt+2
    int l0 = 4*lt, dy0 = 3*dt;
    float su[4][3], sv[4][3];
    #pragma unroll
    for (int k = 0; k < 4; ++k)
      #pragma unroll
      for (int j = 0; j < 3; ++j) { su[k][j] = 0.f; sv[k][j] = 0.f; }
    const float* crp = Cr + l0;
    const float* cip = Ci + l0;
    const float* tp = g_P + 2*dy0;
    #pragma unroll 3
    for (int om2 = 0; om2 < NBIN; ++om2) {
      float4 c4 = *(const float4*)&crp[om2*CLAG];
      float4 i4 = *(const float4*)&cip[om2*CLAG];
      float2 t0 = *(const float2*)&tp[om2*128];
      float2 t1 = *(const float2*)&tp[om2*128 + 2];
      float2 t2 = *(const float2*)&tp[om2*128 + 4];
      float cc[4] = {c4.x, c4.y, c4.z, c4.w};
      float ii[4] = {i4.x, i4.y, i4.z, i4.w};
      float co[3] = {t0.x, t1.x, t2.x};
      float si[3] = {t0.y, t1.y, t2.y};
      #pragma unroll
      for (int k = 0; k < 4; ++k)
        #pragma unroll
        for (int j = 0; j < 3; ++j) {
          su[k][j] += cc[k]*co[j];
          sv[k][j] += ii[k]*si[j];
        }
    }
    #pragma unroll
    for (int k = 0; k < 4; ++k) {
      int lagIdx = l0 + k;          // lag = lagIdx - 49 (valid <= 98)
      if (lagIdx <= 98) {
        int row = lagIdx + 1;
        #pragma unroll
        for (int j = 0; j < 3; ++j) {
          int dy = dy0 + j;
          if (dy <= 49) {
            float vp = su[k][j] - sv[k][j];   // col = 50 + dy
            float vm = su[k][j] + sv[k][j];   // col = 50 - dy
            int posp = row*SD + (50 + dy);
            int posm = row*SD + (50 - dy);
            if (vp < bestV || (vp == bestV && posp < bestP)) { bestV = vp; bestP = posp; }
            if (vm < bestV || (vm == bestV && posm < bestP)) { bestV = vm; bestP = posm; }
          }
        }
      }
    }
  }

  // reduce: wave shuffle lex-min, then 8-entry LDS final
  #pragma unroll
  for (int off = 32; off > 0; off >>= 1) {
    float v2 = __shfl_xor(bestV, off, 64);
    int   p2 = __shfl_xor(bestP, off, 64);
    if (v2 < bestV || (v2 == bestV && p2 < bestP)) { bestV = v2; bestP = p2; }
  }
  if (lane == 0) { sRedV[wid] = bestV; sRedP[wid] = bestP; }
  __syncthreads();
  if (tid == 0) {
    float bv = sRedV[0]; int bp = sRedP[0];
    for (int w = 1; w < 8; ++w) {
      float v2 = sRedV[w]; int p2 = sRedP[w];
      if (v2 < bv || (v2 == bv && p2 < bp)) { bv = v2; bp = p2; }
    }
    g_resV[bid] = bv; g_resP[bid] = bp;
  }
}

// ================= final: reduce over angles, emit outputs =================
__global__ void k_final(float* __restrict__ out) {
  int b = threadIdx.x;
  if (b >= NB) return;
  float bv = 0.f; int bp = 0; int ba = 0;
  for (int a = 0; a < NANG; ++a) {
    float v = g_resV[b*NANG + a];
    if (v < bv) { bv = v; bp = g_resP[b*NANG + a]; ba = a; }
  }
  out[b] = 0.05235987755982988f * (float)ba;
  out[NB + 2*b]     = (float)(bp / SD) - 50.f;
  out[NB + 2*b + 1] = (float)(bp % SD) - 50.f;
}

extern "C" void kernel_launch(void* const* d_in, const int* in_sizes, int n_in,
                              void* d_out, int out_size, void* d_ws, size_t ws_size,
                              hipStream_t stream) {
  const float* rec = (const float*)d_in[0];
  const float* lig = (const float*)d_in[1];
  const float* wr  = (const float*)d_in[2];
  const float* br  = (const float*)d_in[3];
  const float* wsc = (const float*)d_in[4];
  (void)in_sizes; (void)n_in; (void)out_size; (void)d_ws; (void)ws_size;
  hipLaunchKernelGGL(k_prep, dim3(NB+1), dim3(512), 0, stream, rec, lig, wr, br, wsc);
  hipLaunchKernelGGL(k_main, dim3(NANG*NB), dim3(512), 0, stream);
  hipLaunchKernelGGL(k_final, dim3(1), dim3(64), 0, stream, (float*)d_out);
}

// Round 7
// 295.746 us; speedup vs baseline: 1.3218x; 1.3218x over previous
//
#include <hip/hip_runtime.h>
#include <math.h>

#define NANG 120
#define NB   16
#define H    50
#define SD   100
#define NBIN 51        // rfft bins of length-100
#define PADB 7         // top pad rows of B-hat (rows -7..-1 zero)
#define BROWS 69       // stored rows: r in [-7, 61]
#define BST  106       // B-hat row stride
#define WST  104       // g_W row stride
#define RTST 52        // Rt row stride
#define CLAG 104       // C lag dim (13 tiles * 8)
#define AX   58        // g_Arec x rows (50 real + 8 zero pad)

// ---- device-global scratch ----
__device__ __align__(16) float g_Arec[NB*2*AX*NBIN*2 + 64]; // [b][c][x][om][2], x 50..57 zero
__device__ __align__(16) float g_ligc[NB*2*H*H];            // [b][c][y][x]
__device__ __align__(16) float g_W[H*WST];                  // [y][2*om+p] = (cos, -sin)
__device__ __align__(16) float g_P[NBIN*128 + 64];          // [om][2*dy+p] = (cos,sin), dy 0..49
__device__ __align__(16) float g_C[(size_t)NANG*NB*2*NBIN*CLAG/ NBIN * NBIN]; // [bid][p][om][104]
__device__ float g_resV[NANG*NB];
__device__ int   g_resP[NANG*NB];

// 8-lag tile d0 bases per wave (2 slots, 127 = none). All active waves: exactly 14 groups.
__device__ const int g_s8[8][2] = {
  {-1,127},{-9,47},{7,-49},{-17,39},{15,-41},{-25,31},{23,-33},{127,127}
};

// ================= prep: conv+relu+combine, rec spectrum, tables =================
__global__ __launch_bounds__(512) void k_prep(const float* __restrict__ rec,
                                              const float* __restrict__ lig,
                                              const float* __restrict__ wr,
                                              const float* __restrict__ br,
                                              const float* __restrict__ wsc) {
  const int blk = blockIdx.x;
  const int tid = threadIdx.x;
  if (blk == NB) {
    for (int u = tid; u < H*WST; u += 512) {
      int y = u / WST, col = u % WST;
      float v = 0.f;
      if (col < 2*NBIN) {
        int om = col >> 1;
        int k = (om * y) % SD;
        double ang = 6.283185307179586 * (double)k / 100.0;
        v = (col & 1) ? (float)(-sin(ang)) : (float)cos(ang);
      }
      g_W[u] = v;
    }
    for (int u = tid; u < NBIN*128; u += 512) {
      int om = u >> 7, q = u & 127;
      int dy = q >> 1;
      float v = 0.f;
      if (dy <= 49) {
        int k = (om * dy) % SD;
        double ang = 6.283185307179586 * (double)k / 100.0;
        v = (q & 1) ? (float)sin(ang) : (float)cos(ang);
      }
      g_P[u] = v;
    }
    return;
  }
  const int b = blk;
  __shared__ float recf[2*H*H];
  __shared__ float tbl[SD*2];
  for (int k = tid; k < SD; k += 512) {
    double ang = 6.283185307179586 * (double)k / 100.0;
    tbl[2*k]   = (float)cos(ang);
    tbl[2*k+1] = (float)sin(ang);
  }
  const float* rimg = rec + b*H*H;
  const float* limg = lig + b*H*H;
  for (int p = tid; p < H*H; p += 512) {
    int i = p / H, j = p - (p/H)*H;
    float ar0 = br[0], ar1 = br[1], al0 = br[0], al1 = br[1];
    for (int di = 0; di < 3; ++di) {
      int ii = i + di - 1;
      if (ii < 0 || ii >= H) continue;
      for (int dj = 0; dj < 3; ++dj) {
        int jj = j + dj - 1;
        if (jj < 0 || jj >= H) continue;
        float rv = rimg[ii*H+jj], lv = limg[ii*H+jj];
        float w0 = wr[di*3 + dj], w1 = wr[9 + di*3 + dj];
        ar0 += w0*rv; ar1 += w1*rv; al0 += w0*lv; al1 += w1*lv;
      }
    }
    ar0 = fmaxf(ar0, 0.f); ar1 = fmaxf(ar1, 0.f);
    al0 = fmaxf(al0, 0.f); al1 = fmaxf(al1, 0.f);
    recf[p] = ar0; recf[H*H + p] = ar1;
    g_ligc[((b*2+0)*H + i)*H + j] = wsc[0]*al0 + wsc[1]*al1;
    g_ligc[((b*2+1)*H + i)*H + j] = wsc[2]*al0 + wsc[3]*al1;
  }
  for (int u = tid; u < 2*8*102; u += 512) {
    int c = u / 816; int r = u % 816;
    int x = 50 + r / 102; int q = r % 102;
    g_Arec[((b*2+c)*AX + x)*102 + q] = 0.f;
  }
  __syncthreads();
  for (int u = tid; u < 2*H*NBIN; u += 512) {
    int om = u % NBIN; int rest = u / NBIN; int x = rest % H; int c = rest / H;
    const float* row = recf + (c*H + x)*H;
    float sr = 0.f, si = 0.f;
    int k = 0;
    for (int y = 0; y < H; ++y) {
      float rv = row[y];
      sr += rv * tbl[2*k];
      si -= rv * tbl[2*k+1];
      k += om; if (k >= SD) k -= SD;
    }
    float* dst = g_Arec + ((b*2+c)*AX + x)*102 + 2*om;
    dst[0] = sr; dst[1] = si;
  }
}

#define STEP8(uu) do { \
  float Ar = ar_[(uu)&7], Ai = ai_[(uu)&7]; \
  { const int sl=(uu)&7;     cr0 += Ar*br_[sl]+Ai*bi_[sl]; ci0 += Ar*bi_[sl]-Ai*br_[sl]; } \
  { const int sl=((uu)+1)&7; cr1 += Ar*br_[sl]+Ai*bi_[sl]; ci1 += Ar*bi_[sl]-Ai*br_[sl]; } \
  { const int sl=((uu)+2)&7; cr2 += Ar*br_[sl]+Ai*bi_[sl]; ci2 += Ar*bi_[sl]-Ai*br_[sl]; } \
  { const int sl=((uu)+3)&7; cr3 += Ar*br_[sl]+Ai*bi_[sl]; ci3 += Ar*bi_[sl]-Ai*br_[sl]; } \
  { const int sl=((uu)+4)&7; cr4 += Ar*br_[sl]+Ai*bi_[sl]; ci4 += Ar*bi_[sl]-Ai*br_[sl]; } \
  { const int sl=((uu)+5)&7; cr5 += Ar*br_[sl]+Ai*bi_[sl]; ci5 += Ar*bi_[sl]-Ai*br_[sl]; } \
  { const int sl=((uu)+6)&7; cr6 += Ar*br_[sl]+Ai*bi_[sl]; ci6 += Ar*bi_[sl]-Ai*br_[sl]; } \
  { const int sl=((uu)+7)&7; cr7 += Ar*br_[sl]+Ai*bi_[sl]; ci7 += Ar*bi_[sl]-Ai*br_[sl]; } \
} while(0)

// 8-lag tile: channels looped INSIDE (both resident in sB); scalars die at tile end.
#define TILE8(D0) do { \
  const int d0 = (D0); \
  const int x_lo = max(0, -(d0+7)); \
  const int x_hi = min(H, H - d0); \
  const int ng = (x_hi - x_lo + 7) >> 3; \
  float cr0=0,cr1=0,cr2=0,cr3=0,cr4=0,cr5=0,cr6=0,cr7=0; \
  float ci0=0,ci1=0,ci2=0,ci3=0,ci4=0,ci5=0,ci6=0,ci7=0; \
  _Pragma("unroll 1") \
  for (int c = 0; c < 2; ++c) { \
    const float* Ap = g_Arec + ((b*2+c)*AX + x_lo)*102 + 2*om; \
    const float* Bp = sB + c*(BROWS*BST) + (PADB + x_lo + d0)*BST + 2*om; \
    float br_[8], bi_[8], ar_[8], ai_[8]; \
    _Pragma("unroll") \
    for (int s = 0; s < 8; ++s) { \
      float2 bv = *(const float2*)&Bp[s*BST]; \
      br_[s] = bv.x; bi_[s] = bv.y; \
      float2 av = *(const float2*)&Ap[s*102]; \
      ar_[s] = av.x; ai_[s] = av.y; \
    } \
    _Pragma("unroll 1") \
    for (int g = 0; g < ng-1; ++g) { \
      _Pragma("unroll") \
      for (int u = 0; u < 8; ++u) { \
        STEP8(u); \
        float2 bv = *(const float2*)&Bp[(u+8)*BST]; \
        br_[u] = bv.x; bi_[u] = bv.y; \
        float2 av = *(const float2*)&Ap[(u+8)*102]; \
        ar_[u] = av.x; ai_[u] = av.y; \
      } \
      Bp += 8*BST; Ap += 8*102; \
    } \
    _Pragma("unroll") \
    for (int u = 0; u < 8; ++u) { \
      STEP8(u); \
      if (u < 7) { \
        float2 bv = *(const float2*)&Bp[(u+8)*BST]; \
        br_[u] = bv.x; bi_[u] = bv.y; \
      } \
    } \
  } \
  if (omValid) { \
    const float sc = (om == 0 || om == 50) ? 0.5f : 1.0f; \
    float* dst = g_C + (size_t)bid*10608 + om*CLAG + (d0 + 49); \
    float4 v0 = {cr0*sc, cr1*sc, cr2*sc, cr3*sc}; \
    float4 v1 = {cr4*sc, cr5*sc, cr6*sc, cr7*sc}; \
    float4 w0 = {ci0*sc, ci1*sc, ci2*sc, ci3*sc}; \
    float4 w1 = {ci4*sc, ci5*sc, ci6*sc, ci7*sc}; \
    *(float4*)&dst[0] = v0; *(float4*)&dst[4] = v1; \
    *(float4*)&dst[5304] = w0; *(float4*)&dst[5308] = w1; \
  } \
} while(0)

// ================= main: per (angle,batch) block, 512 threads =================
__global__ __launch_bounds__(512, 4) void k_main() {
  const int bid = blockIdx.x;
  const int a = bid % NANG;
  const int b = bid / NANG;
  const int tid = threadIdx.x;

  // LDS (words):
  //   [0..14628)       sB [2][69][106]   (dead after P3)
  //   [0..10608)       Cr[51][104], Ci[51][104]  (staged back after P3)
  //   [14628..19828)   Rt0/Rt1 [50][52] each (dead after P2)
  //   [19828..19844)   reduction
  __shared__ __align__(16) float sMem[19844];
  float* sB  = sMem;
  float* Rt0 = sMem + 14628;
  float* Rt1 = sMem + 17228;
  float* Cr  = sMem;
  float* Ci  = sMem + 5304;
  float* sRedV = sMem + 19828;
  int*   sRedP = (int*)(sMem + 19836);

  // P0: zero pad rows of sB (stored rows 0..6 and 57..68, both channels)
  for (int u = tid; u < 2*19*BST; u += 512) {
    int ch = u / (19*BST);
    int r  = (u % (19*BST)) / BST;
    int col = u % BST;
    int row = (r < PADB) ? r : r + 50;
    sB[ch*(BROWS*BST) + row*BST + col] = 0.f;
  }

  // P1: bilinear rotation of combined ligand features -> Rt0/Rt1 ([col j][row i])
  float angf = 0.05235987755982988f * (float)a;
  float ca = cosf(angf), sa = sinf(angf);
  const float* L0 = g_ligc + (b*2+0)*H*H;
  const float* L1 = g_ligc + (b*2+1)*H*H;
  for (int p = tid; p < H*H; p += 512) {
    int i = p / H, j = p - (p/H)*H;
    float gy = -1.f + (float)i*(2.f/49.f);
    float gx = -1.f + (float)j*(2.f/49.f);
    float x_in = ca*gx - sa*gy;
    float y_in = sa*gx + ca*gy;
    float px = (x_in + 1.f)*0.5f*49.f;
    float py = (y_in + 1.f)*0.5f*49.f;
    float fx = floorf(px), fy = floorf(py);
    int x0 = (int)fx, y0 = (int)fy;
    int x1 = x0 + 1, y1 = y0 + 1;
    float wx1 = px - fx, wx0 = 1.f - wx1;
    float wy1 = py - fy, wy0 = 1.f - wy1;
    float v0 = 0.f, v1 = 0.f;
    if (y0 >= 0 && y0 < H) {
      if (x0 >= 0 && x0 < H) { float w = wy0*wx0; int o = y0*H+x0; v0 += w*L0[o]; v1 += w*L1[o]; }
      if (x1 >= 0 && x1 < H) { float w = wy0*wx1; int o = y0*H+x1; v0 += w*L0[o]; v1 += w*L1[o]; }
    }
    if (y1 >= 0 && y1 < H) {
      if (x0 >= 0 && x0 < H) { float w = wy1*wx0; int o = y1*H+x0; v0 += w*L0[o]; v1 += w*L1[o]; }
      if (x1 >= 0 && x1 < H) { float w = wy1*wx1; int o = y1*H+x1; v0 += w*L0[o]; v1 += w*L1[o]; }
    }
    Rt0[j*RTST + i] = v0;
    Rt1[j*RTST + i] = v1;
  }
  __syncthreads();

  // P2: y-DFT of rotated rows -> sB, both channels, one round (442 units)
  if (tid < 442) {
    int c = tid / 221;
    int r = tid % 221;
    int cg = r % 17;            // col group (6 words), fast across lanes
    int it = r / 17;            // 0..12
    int i0 = it*4;
    int col0 = 6*cg;
    float pacc[4][6];
    #pragma unroll
    for (int p = 0; p < 4; ++p)
      #pragma unroll
      for (int q = 0; q < 6; ++q) pacc[p][q] = 0.f;
    const float* rtc = Rt0 + c*(H*RTST) + i0;
    const float* wt = g_W + col0;
    #pragma unroll 2
    for (int y = 0; y < H; ++y) {
      float4 rv = *(const float4*)&rtc[y*RTST];
      float ww[6];
      #pragma unroll
      for (int q = 0; q < 3; ++q) {
        float2 w2 = *(const float2*)&wt[y*WST + 2*q];
        ww[2*q] = w2.x; ww[2*q+1] = w2.y;
      }
      float rr[4] = {rv.x, rv.y, rv.z, rv.w};
      #pragma unroll
      for (int p = 0; p < 4; ++p)
        #pragma unroll
        for (int q = 0; q < 6; ++q) pacc[p][q] += rr[p]*ww[q];
    }
    float* dst = sB + c*(BROWS*BST) + col0;
    #pragma unroll
    for (int p = 0; p < 4; ++p) {
      int i = i0 + p;
      if (i < H) {
        #pragma unroll
        for (int q = 0; q < 3; ++q) {
          float2 o = {pacc[p][2*q], pacc[p][2*q+1]};
          *(float2*)&dst[(PADB+i)*BST + 2*q] = o;
        }
      }
    }
  }
  __syncthreads();

  const int wid = tid >> 6, lane = tid & 63;
  const int om = (lane <= 50) ? lane : 50;
  const bool omValid = (lane <= 50);
  const int d0A = g_s8[wid][0];
  const int d0B = g_s8[wid][1];

  // P3: 8-lag correlation tiles; scalars die at tile end; C -> global
  if (d0A != 127) { TILE8(d0A); }
  if (d0B != 127) { TILE8(d0B); }
  __syncthreads();   // all sB reads + g_C writes done (block-visible)

  // stage C back into LDS (overlaying dead sB)
  {
    const float4* src = (const float4*)(g_C + (size_t)bid*10608);
    float4* dst = (float4*)sMem;
    for (int u = tid; u < 2652; u += 512) dst[u] = src[u];
  }
  __syncthreads();

  // P4: inverse DFT along omega with +-dy symmetry, single round (442 units)
  float bestV = 3.0e38f; int bestP = 0;
  if (tid < 442) {
    int lt = tid % 26;          // lag tile: lagIdx 4*lt..4*lt+3
    int dt = tid / 26;          // dy tile: 3*dt..3*dt+2
    int l0 = 4*lt, dy0 = 3*dt;
    float su[4][3], sv[4][3];
    #pragma unroll
    for (int k = 0; k < 4; ++k)
      #pragma unroll
      for (int j = 0; j < 3; ++j) { su[k][j] = 0.f; sv[k][j] = 0.f; }
    const float* crp = Cr + l0;
    const float* cip = Ci + l0;
    const float* tp = g_P + 2*dy0;
    #pragma unroll 3
    for (int om2 = 0; om2 < NBIN; ++om2) {
      float4 c4 = *(const float4*)&crp[om2*CLAG];
      float4 i4 = *(const float4*)&cip[om2*CLAG];
      float2 t0 = *(const float2*)&tp[om2*128];
      float2 t1 = *(const float2*)&tp[om2*128 + 2];
      float2 t2 = *(const float2*)&tp[om2*128 + 4];
      float cc[4] = {c4.x, c4.y, c4.z, c4.w};
      float ii[4] = {i4.x, i4.y, i4.z, i4.w};
      float co[3] = {t0.x, t1.x, t2.x};
      float si[3] = {t0.y, t1.y, t2.y};
      #pragma unroll
      for (int k = 0; k < 4; ++k)
        #pragma unroll
        for (int j = 0; j < 3; ++j) {
          su[k][j] += cc[k]*co[j];
          sv[k][j] += ii[k]*si[j];
        }
    }
    #pragma unroll
    for (int k = 0; k < 4; ++k) {
      int lagIdx = l0 + k;          // lag = lagIdx - 49 (valid <= 98)
      if (lagIdx <= 98) {
        int row = lagIdx + 1;
        #pragma unroll
        for (int j = 0; j < 3; ++j) {
          int dy = dy0 + j;
          if (dy <= 49) {
            float vp = su[k][j] - sv[k][j];   // col = 50 + dy
            float vm = su[k][j] + sv[k][j];   // col = 50 - dy
            int posp = row*SD + (50 + dy);
            int posm = row*SD + (50 - dy);
            if (vp < bestV || (vp == bestV && posp < bestP)) { bestV = vp; bestP = posp; }
            if (vm < bestV || (vm == bestV && posm < bestP)) { bestV = vm; bestP = posm; }
          }
        }
      }
    }
  }

  // reduce: wave shuffle lex-min, then 8-entry LDS final
  #pragma unroll
  for (int off = 32; off > 0; off >>= 1) {
    float v2 = __shfl_xor(bestV, off, 64);
    int   p2 = __shfl_xor(bestP, off, 64);
    if (v2 < bestV || (v2 == bestV && p2 < bestP)) { bestV = v2; bestP = p2; }
  }
  if (lane == 0) { sRedV[wid] = bestV; sRedP[wid] = bestP; }
  __syncthreads();
  if (tid == 0) {
    float bv = sRedV[0]; int bp = sRedP[0];
    for (int w = 1; w < 8; ++w) {
      float v2 = sRedV[w]; int p2 = sRedP[w];
      if (v2 < bv || (v2 == bv && p2 < bp)) { bv = v2; bp = p2; }
    }
    g_resV[bid] = bv; g_resP[bid] = bp;
  }
}

// ================= final: reduce over angles, emit outputs =================
__global__ void k_final(float* __restrict__ out) {
  int b = threadIdx.x;
  if (b >= NB) return;
  float bv = 0.f; int bp = 0; int ba = 0;
  for (int a = 0; a < NANG; ++a) {
    float v = g_resV[b*NANG + a];
    if (v < bv) { bv = v; bp = g_resP[b*NANG + a]; ba = a; }
  }
  out[b] = 0.05235987755982988f * (float)ba;
  out[NB + 2*b]     = (float)(bp / SD) - 50.f;
  out[NB + 2*b + 1] = (float)(bp % SD) - 50.f;
}

extern "C" void kernel_launch(void* const* d_in, const int* in_sizes, int n_in,
                              void* d_out, int out_size, void* d_ws, size_t ws_size,
                              hipStream_t stream) {
  const float* rec = (const float*)d_in[0];
  const float* lig = (const float*)d_in[1];
  const float* wr  = (const float*)d_in[2];
  const float* br  = (const float*)d_in[3];
  const float* wsc = (const float*)d_in[4];
  (void)in_sizes; (void)n_in; (void)out_size; (void)d_ws; (void)ws_size;
  hipLaunchKernelGGL(k_prep, dim3(NB+1), dim3(512), 0, stream, rec, lig, wr, br, wsc);
  hipLaunchKernelGGL(k_main, dim3(NANG*NB), dim3(512), 0, stream);
  hipLaunchKernelGGL(k_final, dim3(1), dim3(64), 0, stream, (float*)d_out);
}

// Round 8
// 279.339 us; speedup vs baseline: 1.3994x; 1.0587x over previous
//
#include <hip/hip_runtime.h>
#include <math.h>

#define NANG 120
#define NB   16
#define H    50
#define SD   100
#define NBIN 51        // rfft bins of length-100
#define PADB 7         // top pad rows of B-hat (rows -7..-1 zero)
#define BROWS 69       // stored rows: r in [-7, 61]
#define BST  106       // B-hat row stride
#define WST  104       // g_W row stride
#define RTST 52        // Rt row stride
#define CLAG 100       // C lag dim (lagIdx 0..99; lags 51..54 of last tile dropped)
#define AX   58        // g_Arec x rows (50 real + 8 zero pad)

// ---- device-global scratch ----
__device__ __align__(16) float g_Arec[NB*2*AX*NBIN*2 + 64]; // [b][c][x][om][2], x 50..57 zero
__device__ __align__(16) float g_ligc[NB*2*H*H];            // [b][c][y][x]
__device__ __align__(16) float g_W[H*WST];                  // [y][2*om+p] = (cos, -sin)
__device__ __align__(16) float g_P[NBIN*128 + 64];          // [om][2*dy+p] = (cos,sin), dy 0..49
__device__ __align__(16) float g_C[(size_t)NANG*NB*5100];   // Ci only: [bid][om][100]
__device__ unsigned long long g_key[NB];

// 8-lag tile d0 bases per wave (2 slots, 127 = none). All active waves: exactly 14 groups.
__device__ const int g_s8[8][2] = {
  {-1,127},{-9,47},{7,-49},{-17,39},{15,-41},{-25,31},{23,-33},{127,127}
};

// ================= prep: conv+relu+combine, rec spectrum, tables =================
// grid = NB*4 + 1. blocks (b,part): part = blk&3 handles om in [13*part, ...)
__global__ __launch_bounds__(512) void k_prep(const float* __restrict__ rec,
                                              const float* __restrict__ lig,
                                              const float* __restrict__ wr,
                                              const float* __restrict__ br,
                                              const float* __restrict__ wsc) {
  const int blk = blockIdx.x;
  const int tid = threadIdx.x;
  if (blk == NB*4) {
    for (int u = tid; u < H*WST; u += 512) {
      int y = u / WST, col = u % WST;
      float v = 0.f;
      if (col < 2*NBIN) {
        int om = col >> 1;
        int k = (om * y) % SD;
        double ang = 6.283185307179586 * (double)k / 100.0;
        v = (col & 1) ? (float)(-sin(ang)) : (float)cos(ang);
      }
      g_W[u] = v;
    }
    for (int u = tid; u < NBIN*128; u += 512) {
      int om = u >> 7, q = u & 127;
      int dy = q >> 1;
      float v = 0.f;
      if (dy <= 49) {
        int k = (om * dy) % SD;
        double ang = 6.283185307179586 * (double)k / 100.0;
        v = (q & 1) ? (float)sin(ang) : (float)cos(ang);
      }
      g_P[u] = v;
    }
    // seed keys: val=0.0 (mapped 0x80000000), a=0, pos=0
    for (int i = tid; i < NB; i += 512) g_key[i] = (0x80000000ULL << 21);
    return;
  }
  const int b = blk >> 2;
  const int part = blk & 3;
  const int omBase = part * 13;
  const int nOm = (part == 3) ? 12 : 13;
  __shared__ float recf[2*H*H];
  __shared__ float tbl[SD*2];
  for (int k = tid; k < SD; k += 512) {
    double ang = 6.283185307179586 * (double)k / 100.0;
    tbl[2*k]   = (float)cos(ang);
    tbl[2*k+1] = (float)sin(ang);
  }
  const float* rimg = rec + b*H*H;
  const float* limg = lig + b*H*H;
  for (int p = tid; p < H*H; p += 512) {
    int i = p / H, j = p - (p/H)*H;
    float ar0 = br[0], ar1 = br[1], al0 = br[0], al1 = br[1];
    for (int di = 0; di < 3; ++di) {
      int ii = i + di - 1;
      if (ii < 0 || ii >= H) continue;
      for (int dj = 0; dj < 3; ++dj) {
        int jj = j + dj - 1;
        if (jj < 0 || jj >= H) continue;
        float rv = rimg[ii*H+jj], lv = limg[ii*H+jj];
        float w0 = wr[di*3 + dj], w1 = wr[9 + di*3 + dj];
        ar0 += w0*rv; ar1 += w1*rv; al0 += w0*lv; al1 += w1*lv;
      }
    }
    ar0 = fmaxf(ar0, 0.f); ar1 = fmaxf(ar1, 0.f);
    recf[p] = ar0; recf[H*H + p] = ar1;
    if (part == 0) {
      al0 = fmaxf(al0, 0.f); al1 = fmaxf(al1, 0.f);
      g_ligc[((b*2+0)*H + i)*H + j] = wsc[0]*al0 + wsc[1]*al1;
      g_ligc[((b*2+1)*H + i)*H + j] = wsc[2]*al0 + wsc[3]*al1;
    }
  }
  if (part == 0) {
    for (int u = tid; u < 2*8*102; u += 512) {
      int c = u / 816; int r = u % 816;
      int x = 50 + r / 102; int q = r % 102;
      g_Arec[((b*2+c)*AX + x)*102 + q] = 0.f;
    }
  }
  __syncthreads();
  for (int u = tid; u < 2*H*nOm; u += 512) {
    int om = omBase + u % nOm;
    int rest = u / nOm; int x = rest % H; int c = rest / H;
    const float* row = recf + (c*H + x)*H;
    float sr = 0.f, si = 0.f;
    int k = 0;
    for (int y = 0; y < H; ++y) {
      float rv = row[y];
      sr += rv * tbl[2*k];
      si -= rv * tbl[2*k+1];
      k += om; if (k >= SD) k -= SD;
    }
    float* dst = g_Arec + ((b*2+c)*AX + x)*102 + 2*om;
    dst[0] = sr; dst[1] = si;
  }
}

#define STEP8(uu) do { \
  float Ar = ar_[(uu)&7], Ai = ai_[(uu)&7]; \
  { const int sl=(uu)&7;     cr0 += Ar*br_[sl]+Ai*bi_[sl]; ci0 += Ar*bi_[sl]-Ai*br_[sl]; } \
  { const int sl=((uu)+1)&7; cr1 += Ar*br_[sl]+Ai*bi_[sl]; ci1 += Ar*bi_[sl]-Ai*br_[sl]; } \
  { const int sl=((uu)+2)&7; cr2 += Ar*br_[sl]+Ai*bi_[sl]; ci2 += Ar*bi_[sl]-Ai*br_[sl]; } \
  { const int sl=((uu)+3)&7; cr3 += Ar*br_[sl]+Ai*bi_[sl]; ci3 += Ar*bi_[sl]-Ai*br_[sl]; } \
  { const int sl=((uu)+4)&7; cr4 += Ar*br_[sl]+Ai*bi_[sl]; ci4 += Ar*bi_[sl]-Ai*br_[sl]; } \
  { const int sl=((uu)+5)&7; cr5 += Ar*br_[sl]+Ai*bi_[sl]; ci5 += Ar*bi_[sl]-Ai*br_[sl]; } \
  { const int sl=((uu)+6)&7; cr6 += Ar*br_[sl]+Ai*bi_[sl]; ci6 += Ar*bi_[sl]-Ai*br_[sl]; } \
  { const int sl=((uu)+7)&7; cr7 += Ar*br_[sl]+Ai*bi_[sl]; ci7 += Ar*bi_[sl]-Ai*br_[sl]; } \
} while(0)

// 8-lag tile: channels looped INSIDE (both resident in sB); scalars die at tile end.
// Cr -> LDS (CrL), Ci -> g_C. d0==47 clips the second float4 (lags 51..54 unused).
#define TILE8(D0) do { \
  const int d0 = (D0); \
  const int x_lo = max(0, -(d0+7)); \
  const int x_hi = min(H, H - d0); \
  const int ng = (x_hi - x_lo + 7) >> 3; \
  float cr0=0,cr1=0,cr2=0,cr3=0,cr4=0,cr5=0,cr6=0,cr7=0; \
  float ci0=0,ci1=0,ci2=0,ci3=0,ci4=0,ci5=0,ci6=0,ci7=0; \
  _Pragma("unroll 1") \
  for (int c = 0; c < 2; ++c) { \
    const float* Ap = g_Arec + ((b*2+c)*AX + x_lo)*102 + 2*om; \
    const float* Bp = sB + c*(BROWS*BST) + (PADB + x_lo + d0)*BST + 2*om; \
    float br_[8], bi_[8], ar_[8], ai_[8]; \
    _Pragma("unroll") \
    for (int s = 0; s < 8; ++s) { \
      float2 bv = *(const float2*)&Bp[s*BST]; \
      br_[s] = bv.x; bi_[s] = bv.y; \
      float2 av = *(const float2*)&Ap[s*102]; \
      ar_[s] = av.x; ai_[s] = av.y; \
    } \
    _Pragma("unroll 1") \
    for (int g = 0; g < ng-1; ++g) { \
      _Pragma("unroll") \
      for (int u = 0; u < 8; ++u) { \
        STEP8(u); \
        float2 bv = *(const float2*)&Bp[(u+8)*BST]; \
        br_[u] = bv.x; bi_[u] = bv.y; \
        float2 av = *(const float2*)&Ap[(u+8)*102]; \
        ar_[u] = av.x; ai_[u] = av.y; \
      } \
      Bp += 8*BST; Ap += 8*102; \
    } \
    _Pragma("unroll") \
    for (int u = 0; u < 8; ++u) { \
      STEP8(u); \
      if (u < 7) { \
        float2 bv = *(const float2*)&Bp[(u+8)*BST]; \
        br_[u] = bv.x; bi_[u] = bv.y; \
      } \
    } \
  } \
  if (omValid) { \
    const float sc = (om == 0 || om == 50) ? 0.5f : 1.0f; \
    const int base = om*CLAG + (d0 + 49); \
    float* crl = CrL + base; \
    float* gci = g_C + (size_t)bid*5100 + base; \
    float4 v0 = {cr0*sc, cr1*sc, cr2*sc, cr3*sc}; \
    float4 w0 = {ci0*sc, ci1*sc, ci2*sc, ci3*sc}; \
    *(float4*)&crl[0] = v0; \
    *(float4*)&gci[0] = w0; \
    if (d0 != 47) { \
      float4 v1 = {cr4*sc, cr5*sc, cr6*sc, cr7*sc}; \
      float4 w1 = {ci4*sc, ci5*sc, ci6*sc, ci7*sc}; \
      *(float4*)&crl[4] = v1; \
      *(float4*)&gci[4] = w1; \
    } \
  } \
} while(0)

// ================= main: per (angle,batch) block, 512 threads =================
__global__ __launch_bounds__(512, 4) void k_main() {
  const int bid = blockIdx.x;
  const int a = bid % NANG;
  const int b = bid / NANG;
  const int tid = threadIdx.x;

  // LDS (words):
  //   [0..14628)       sB [2][69][106]   (dead after P3)
  //   [14628..19828)   Rt0/Rt1 [50][52] each (dead after P2), then CrL [51][100]
  //   [0..5100)        Ci staged back after P3 (over dead sB)
  //   [5100..10200)    sP: g_P repacked [51][100]
  __shared__ __align__(16) float sMem[19828];
  float* sB  = sMem;
  float* Rt0 = sMem + 14628;
  float* Rt1 = sMem + 17228;
  float* CrL = sMem + 14628;
  float* CiL = sMem;
  float* sP  = sMem + 5100;

  // P0: zero pad rows of sB (stored rows 0..6 and 57..68, both channels)
  for (int u = tid; u < 2*19*BST; u += 512) {
    int ch = u / (19*BST);
    int r  = (u % (19*BST)) / BST;
    int col = u % BST;
    int row = (r < PADB) ? r : r + 50;
    sB[ch*(BROWS*BST) + row*BST + col] = 0.f;
  }

  // P1: bilinear rotation of combined ligand features -> Rt0/Rt1 ([col j][row i])
  float angf = 0.05235987755982988f * (float)a;
  float ca = cosf(angf), sa = sinf(angf);
  const float* L0 = g_ligc + (b*2+0)*H*H;
  const float* L1 = g_ligc + (b*2+1)*H*H;
  for (int p = tid; p < H*H; p += 512) {
    int i = p / H, j = p - (p/H)*H;
    float gy = -1.f + (float)i*(2.f/49.f);
    float gx = -1.f + (float)j*(2.f/49.f);
    float x_in = ca*gx - sa*gy;
    float y_in = sa*gx + ca*gy;
    float px = (x_in + 1.f)*0.5f*49.f;
    float py = (y_in + 1.f)*0.5f*49.f;
    float fx = floorf(px), fy = floorf(py);
    int x0 = (int)fx, y0 = (int)fy;
    int x1 = x0 + 1, y1 = y0 + 1;
    float wx1 = px - fx, wx0 = 1.f - wx1;
    float wy1 = py - fy, wy0 = 1.f - wy1;
    float v0 = 0.f, v1 = 0.f;
    if (y0 >= 0 && y0 < H) {
      if (x0 >= 0 && x0 < H) { float w = wy0*wx0; int o = y0*H+x0; v0 += w*L0[o]; v1 += w*L1[o]; }
      if (x1 >= 0 && x1 < H) { float w = wy0*wx1; int o = y0*H+x1; v0 += w*L0[o]; v1 += w*L1[o]; }
    }
    if (y1 >= 0 && y1 < H) {
      if (x0 >= 0 && x0 < H) { float w = wy1*wx0; int o = y1*H+x0; v0 += w*L0[o]; v1 += w*L1[o]; }
      if (x1 >= 0 && x1 < H) { float w = wy1*wx1; int o = y1*H+x1; v0 += w*L0[o]; v1 += w*L1[o]; }
    }
    Rt0[j*RTST + i] = v0;
    Rt1[j*RTST + i] = v1;
  }
  __syncthreads();

  // P2: y-DFT of rotated rows -> sB, both channels, one round (442 units)
  if (tid < 442) {
    int c = tid / 221;
    int r = tid % 221;
    int cg = r % 17;            // col group (6 words), fast across lanes
    int it = r / 17;            // 0..12
    int i0 = it*4;
    int col0 = 6*cg;
    float pacc[4][6];
    #pragma unroll
    for (int p = 0; p < 4; ++p)
      #pragma unroll
      for (int q = 0; q < 6; ++q) pacc[p][q] = 0.f;
    const float* rtc = Rt0 + c*(H*RTST) + i0;
    const float* wt = g_W + col0;
    #pragma unroll 2
    for (int y = 0; y < H; ++y) {
      float4 rv = *(const float4*)&rtc[y*RTST];
      float ww[6];
      #pragma unroll
      for (int q = 0; q < 3; ++q) {
        float2 w2 = *(const float2*)&wt[y*WST + 2*q];
        ww[2*q] = w2.x; ww[2*q+1] = w2.y;
      }
      float rr[4] = {rv.x, rv.y, rv.z, rv.w};
      #pragma unroll
      for (int p = 0; p < 4; ++p)
        #pragma unroll
        for (int q = 0; q < 6; ++q) pacc[p][q] += rr[p]*ww[q];
    }
    float* dst = sB + c*(BROWS*BST) + col0;
    #pragma unroll
    for (int p = 0; p < 4; ++p) {
      int i = i0 + p;
      if (i < H) {
        #pragma unroll
        for (int q = 0; q < 3; ++q) {
          float2 o = {pacc[p][2*q], pacc[p][2*q+1]};
          *(float2*)&dst[(PADB+i)*BST + 2*q] = o;
        }
      }
    }
  }
  __syncthreads();

  const int wid = tid >> 6, lane = tid & 63;
  const int om = (lane <= 50) ? lane : 50;
  const bool omValid = (lane <= 50);
  const int d0A = g_s8[wid][0];
  const int d0B = g_s8[wid][1];

  // P3: 8-lag correlation tiles; Cr -> LDS, Ci -> global
  if (d0A != 127) { TILE8(d0A); }
  if (d0B != 127) { TILE8(d0B); }
  __syncthreads();   // sB reads done; CrL + g_C writes visible

  // stage Ci back into LDS + repack g_P -> sP (both over dead sB)
  {
    const float4* src = (const float4*)(g_C + (size_t)bid*5100);
    float4* dst = (float4*)CiL;
    for (int u = tid; u < 1275; u += 512) dst[u] = src[u];
    for (int u = tid; u < 51*50; u += 512) {
      int o = u / 50, q2 = (u % 50)*2;
      *(float2*)&sP[o*100 + q2] = *(const float2*)&g_P[o*128 + q2];
    }
  }
  __syncthreads();

  // P4: inverse DFT along omega with +-dy symmetry, single round (425 units), all-LDS
  float bestV = 3.0e38f; int bestP = 0;
  if (tid < 425) {
    int lt = tid % 25;          // lag tile: lagIdx 4*lt..4*lt+3
    int dt = tid / 25;          // dy tile: 3*dt..3*dt+2
    int l0 = 4*lt, dy0 = 3*dt;
    float su[4][3], sv[4][3];
    #pragma unroll
    for (int k = 0; k < 4; ++k)
      #pragma unroll
      for (int j = 0; j < 3; ++j) { su[k][j] = 0.f; sv[k][j] = 0.f; }
    const float* crp = CrL + l0;
    const float* cip = CiL + l0;
    const float* tp = sP + 2*dy0;
    #pragma unroll 3
    for (int om2 = 0; om2 < NBIN; ++om2) {
      float4 c4 = *(const float4*)&crp[om2*CLAG];
      float4 i4 = *(const float4*)&cip[om2*CLAG];
      float2 t0 = *(const float2*)&tp[om2*100];
      float2 t1 = *(const float2*)&tp[om2*100 + 2];
      float2 t2 = *(const float2*)&tp[om2*100 + 4];
      float cc[4] = {c4.x, c4.y, c4.z, c4.w};
      float ii[4] = {i4.x, i4.y, i4.z, i4.w};
      float co[3] = {t0.x, t1.x, t2.x};
      float si[3] = {t0.y, t1.y, t2.y};
      #pragma unroll
      for (int k = 0; k < 4; ++k)
        #pragma unroll
        for (int j = 0; j < 3; ++j) {
          su[k][j] += cc[k]*co[j];
          sv[k][j] += ii[k]*si[j];
        }
    }
    #pragma unroll
    for (int k = 0; k < 4; ++k) {
      int lagIdx = l0 + k;          // lag = lagIdx - 49 (valid <= 98)
      if (lagIdx <= 98) {
        int row = lagIdx + 1;
        #pragma unroll
        for (int j = 0; j < 3; ++j) {
          int dy = dy0 + j;
          if (dy <= 49) {
            float vp = su[k][j] - sv[k][j];   // col = 50 + dy
            float vm = su[k][j] + sv[k][j];   // col = 50 - dy
            int posp = row*SD + (50 + dy);
            int posm = row*SD + (50 - dy);
            if (vp < bestV || (vp == bestV && posp < bestP)) { bestV = vp; bestP = posp; }
            if (vm < bestV || (vm == bestV && posm < bestP)) { bestV = vm; bestP = posm; }
          }
        }
      }
    }
  }

  // reduce: wave shuffle lex-min, then one 64-bit atomicMin per wave
  #pragma unroll
  for (int off = 32; off > 0; off >>= 1) {
    float v2 = __shfl_xor(bestV, off, 64);
    int   p2 = __shfl_xor(bestP, off, 64);
    if (v2 < bestV || (v2 == bestV && p2 < bestP)) { bestV = v2; bestP = p2; }
  }
  if (lane == 0) {
    unsigned int u = __float_as_uint(bestV);
    u = (u & 0x80000000u) ? ~u : (u | 0x80000000u);
    unsigned long long key = ((unsigned long long)u << 21) |
                             ((unsigned long long)(unsigned)a << 14) |
                             (unsigned long long)(unsigned)bestP;
    atomicMin(&g_key[b], key);
  }
}

// ================= final: decode keys, emit outputs =================
__global__ void k_final(float* __restrict__ out) {
  int b = threadIdx.x;
  if (b >= NB) return;
  unsigned long long key = g_key[b];
  int a   = (int)((key >> 14) & 127ULL);
  int pos = (int)(key & 16383ULL);
  out[b] = 0.05235987755982988f * (float)a;
  out[NB + 2*b]     = (float)(pos / SD) - 50.f;
  out[NB + 2*b + 1] = (float)(pos % SD) - 50.f;
}

extern "C" void kernel_launch(void* const* d_in, const int* in_sizes, int n_in,
                              void* d_out, int out_size, void* d_ws, size_t ws_size,
                              hipStream_t stream) {
  const float* rec = (const float*)d_in[0];
  const float* lig = (const float*)d_in[1];
  const float* wr  = (const float*)d_in[2];
  const float* br  = (const float*)d_in[3];
  const float* wsc = (const float*)d_in[4];
  (void)in_sizes; (void)n_in; (void)out_size; (void)d_ws; (void)ws_size;
  hipLaunchKernelGGL(k_prep, dim3(NB*4+1), dim3(512), 0, stream, rec, lig, wr, br, wsc);
  hipLaunchKernelGGL(k_main, dim3(NANG*NB), dim3(512), 0, stream);
  hipLaunchKernelGGL(k_final, dim3(1), dim3(64), 0, stream, (float*)d_out);
}